// Round 10
// baseline (4109.656 us; speedup 1.0000x reference)
//
#include <hip/hip_runtime.h>

// RNN: s_{t+1} = 0.9*s + 0.1*(relu(s@Wrec^T + (u+inz)@Winp^T) + rn)
// d_out = states (B,T,N) fp32 then outputs (B,T,1) fp32, flat-concat.
//
// R10: resident-W, n-partitioned, IF-synced, PIPELINED exchange.
//   R9 proved the sc0sc1 protocol (no cache maintenance; states IS the
//   exchange medium) at 4.06 ms with ~2.8 us/step of serial sync tail.
//   R10 pipelines it: each thread's k-window lives in exactly one source
//   slice, so peer-window threads spin on that one flag and read the
//   32 floats DIRECTLY from states[t] (64-bit sc0sc1 atomic loads);
//   own-window threads compute immediately from LDS. No staged fetch,
//   no tid0 fan-in spin, 2 barriers/step instead of 4.
//   - 32 groups x PP=4 WGs; group g owns batches 4g..4g+3 (GG=4).
//   - WG p owns n-slice p: W[p*128..+128)[all k] in VGPRs (128 f/thread,
//     pinned by scalar asm "+v" -- R6: unpinned W got re-streamed).
//   - flags[g*4+p] = v  <=>  states[v] slice p published. Monotone, no
//     parity buffers (states addresses are unique per t -> no WAR).
//   - Ordering: payload sc0sc1 stores drain at barrier (compiler emits
//     vmcnt(0) before s_barrier), THEN tid0 stores flag; readers spin on
//     flag then load payload (in-order issue per wave; IF is the single
//     coherence point). asm "memory" fence stops compiler reordering.
// out_proj (states @ Wout.T) is a separate trivial kernel.
// Fallback: R1-style kernel if workspace < 512 B.

#define NN 512
#define BB 128
#define TT 1000
#define NIN 6
#define PP 4                    // n-slices (WGs per group)
#define GG 4                    // batches per group
#define NGRP (BB / GG)          // 32 groups
#define NWG (PP * NGRP)         // 128 workgroups
#define SLICE (NN / PP)         // 128
#define WS_NEED (NWG * sizeof(int))

__global__ void init_flags(int* flags) {
  if (threadIdx.x < NWG) flags[threadIdx.x] = -1;
}

__device__ __forceinline__ float wave_sum(float v) {
  #pragma unroll
  for (int off = 32; off > 0; off >>= 1) v += __shfl_xor(v, off, 64);
  return v;
}

// empty asm with tied SCALAR outputs: values become opaque (non-remat).
__device__ __forceinline__ void pin4(float4& a, float4& b, float4& c, float4& d) {
  asm volatile("" : "+v"(a.x), "+v"(a.y), "+v"(a.z), "+v"(a.w),
                    "+v"(b.x), "+v"(b.y), "+v"(b.z), "+v"(b.w),
                    "+v"(c.x), "+v"(c.y), "+v"(c.z), "+v"(c.w),
                    "+v"(d.x), "+v"(d.y), "+v"(d.z), "+v"(d.w));
}

__global__ __launch_bounds__(512, 1)
void rnn_pipe(const float* __restrict__ u, const float* __restrict__ rnz,
              const float* __restrict__ inz, const float* __restrict__ Wrec,
              const float* __restrict__ Winp, const float* __restrict__ yinit,
              float* __restrict__ states, int* __restrict__ flags) {
  const int tid = threadIdx.x;
  // bid remap: a group's 4 WGs share bid&7 (likely same XCD) - perf only.
  const int xcd = blockIdx.x & 7;
  const int rest = blockIdx.x >> 3;     // 0..15
  const int p = rest & 3;               // my n-slice
  const int g = (rest >> 2) * 8 + xcd;  // my group 0..31

  // phase-A mapping: thread (nq, ks) = 4 n-rows x 32-k window x 4 batches
  const int nq = tid & 31;
  const int n0 = nq << 2;               // local n base
  const int ks = tid >> 5;              // 0..15 (2 per wave, same slice)
  const int k0 = ks << 5;               // global k base of my window
  const int src = k0 >> 7;              // source slice of my window
  const bool own = (src == p);
  const int kl = k0 & (SLICE - 1);      // offset within source slice
  // update mapping: thread = (batch, local n)
  const int ub = tid >> 7;
  const int un = tid & 127;
  const int ung = p * SLICE + un;

  __shared__ __align__(16) float pred[16][GG][SLICE];  // 32 KB
  __shared__ __align__(16) float s_own[GG][SLICE];     // 2 KB
  __shared__ float winp_s[SLICE][NIN];                 // 3 KB
  __shared__ float ubuf[GG][NIN];

  // ---- one-time: W fragment (4 rows x 32 k), Winp, s_0 ----
  float4 w[4][8];
  #pragma unroll
  for (int i = 0; i < 4; ++i) {
    const float* wr = Wrec + (size_t)(p * SLICE + n0 + i) * NN + k0;
    #pragma unroll
    for (int q = 0; q < 8; ++q)
      w[i][q] = *reinterpret_cast<const float4*>(wr + 4 * q);
  }
  for (int i = tid; i < SLICE * NIN; i += 512) {
    const int r = i / NIN, j = i - r * NIN;
    winp_s[r][j] = Winp[(p * SLICE + r) * NIN + j];
  }
  const float yv = yinit[ung];
  float scur = yv;
  s_own[ub][un] = yv;
  __hip_atomic_store(&states[(size_t)(g * GG + ub) * TT * NN + ung], yv,
                     __ATOMIC_RELAXED, __HIP_MEMORY_SCOPE_SYSTEM);
  __syncthreads();  // drains the sc0sc1 stores (vmcnt) + LDS
  const int myflag = g * PP + p;
  const int peerflag = g * PP + src;
  if (tid == 0)
    __hip_atomic_store(&flags[myflag], 0, __ATOMIC_RELAXED,
                       __HIP_MEMORY_SCOPE_SYSTEM);

  for (int t = 0; t < TT - 1; ++t) {
    // pin W live (R6: unpinned W was re-streamed from L2 every step)
    #pragma unroll
    for (int i = 0; i < 4; ++i) {
      pin4(w[i][0], w[i][1], w[i][2], w[i][3]);
      pin4(w[i][4], w[i][5], w[i][6], w[i][7]);
    }

    // early per-step loads (plain, L2-cached inputs; used in update)
    const float rnv = rnz[((size_t)(g * GG + ub) * TT + t) * NN + ung];
    if (tid < GG * NIN) {
      const int b = tid / NIN, j = tid - b * NIN;
      const size_t idx = ((size_t)(g * GG + b) * TT + t) * NIN + j;
      ubuf[b][j] = u[idx] + inz[idx];
    }

    // ---- phase A: 4 n x 32 k x 4 b partial dots (512 fmaf) ----
    float a0[GG], a1[GG], a2[GG], a3[GG];
    #pragma unroll
    for (int b = 0; b < GG; ++b) { a0[b] = 0.f; a1[b] = 0.f; a2[b] = 0.f; a3[b] = 0.f; }

    if (own) {
      // my window is the slice this WG computed last step: LDS broadcast
      #pragma unroll
      for (int b = 0; b < GG; ++b) {
        #pragma unroll
        for (int q = 0; q < 8; ++q) {
          const float4 sv = *reinterpret_cast<const float4*>(&s_own[b][kl + 4 * q]);
          a0[b] = fmaf(w[0][q].x, sv.x, a0[b]); a0[b] = fmaf(w[0][q].y, sv.y, a0[b]);
          a0[b] = fmaf(w[0][q].z, sv.z, a0[b]); a0[b] = fmaf(w[0][q].w, sv.w, a0[b]);
          a1[b] = fmaf(w[1][q].x, sv.x, a1[b]); a1[b] = fmaf(w[1][q].y, sv.y, a1[b]);
          a1[b] = fmaf(w[1][q].z, sv.z, a1[b]); a1[b] = fmaf(w[1][q].w, sv.w, a1[b]);
          a2[b] = fmaf(w[2][q].x, sv.x, a2[b]); a2[b] = fmaf(w[2][q].y, sv.y, a2[b]);
          a2[b] = fmaf(w[2][q].z, sv.z, a2[b]); a2[b] = fmaf(w[2][q].w, sv.w, a2[b]);
          a3[b] = fmaf(w[3][q].x, sv.x, a3[b]); a3[b] = fmaf(w[3][q].y, sv.y, a3[b]);
          a3[b] = fmaf(w[3][q].z, sv.z, a3[b]); a3[b] = fmaf(w[3][q].w, sv.w, a3[b]);
        }
      }
    } else {
      // wait for the ONE peer my window needs, then read direct from IF
      while (__hip_atomic_load(&flags[peerflag], __ATOMIC_RELAXED,
                               __HIP_MEMORY_SCOPE_SYSTEM) < t)
        __builtin_amdgcn_s_sleep(1);
      asm volatile("" ::: "memory");  // no payload-load hoisting above spin
      #pragma unroll
      for (int b = 0; b < GG; ++b) {
        const unsigned long long* sb8 = reinterpret_cast<const unsigned long long*>(
            states + ((size_t)(g * GG + b) * TT + t) * NN + k0);
        float xs[32];
        #pragma unroll
        for (int i = 0; i < 16; ++i) {
          const unsigned long long v = __hip_atomic_load(
              sb8 + i, __ATOMIC_RELAXED, __HIP_MEMORY_SCOPE_SYSTEM);
          xs[2 * i]     = __uint_as_float((unsigned int)v);
          xs[2 * i + 1] = __uint_as_float((unsigned int)(v >> 32));
        }
        #pragma unroll
        for (int q = 0; q < 8; ++q) {
          const float svx = xs[4 * q], svy = xs[4 * q + 1];
          const float svz = xs[4 * q + 2], svw = xs[4 * q + 3];
          a0[b] = fmaf(w[0][q].x, svx, a0[b]); a0[b] = fmaf(w[0][q].y, svy, a0[b]);
          a0[b] = fmaf(w[0][q].z, svz, a0[b]); a0[b] = fmaf(w[0][q].w, svw, a0[b]);
          a1[b] = fmaf(w[1][q].x, svx, a1[b]); a1[b] = fmaf(w[1][q].y, svy, a1[b]);
          a1[b] = fmaf(w[1][q].z, svz, a1[b]); a1[b] = fmaf(w[1][q].w, svw, a1[b]);
          a2[b] = fmaf(w[2][q].x, svx, a2[b]); a2[b] = fmaf(w[2][q].y, svy, a2[b]);
          a2[b] = fmaf(w[2][q].z, svz, a2[b]); a2[b] = fmaf(w[2][q].w, svw, a2[b]);
          a3[b] = fmaf(w[3][q].x, svx, a3[b]); a3[b] = fmaf(w[3][q].y, svy, a3[b]);
          a3[b] = fmaf(w[3][q].z, svz, a3[b]); a3[b] = fmaf(w[3][q].w, svw, a3[b]);
        }
      }
    }
    #pragma unroll
    for (int b = 0; b < GG; ++b)
      *reinterpret_cast<float4*>(&pred[ks][b][n0]) =
          make_float4(a0[b], a1[b], a2[b], a3[b]);
    __syncthreads();  // #1: pred + ubuf visible

    // ---- update: thread (ub, un); s_old lives in register scur ----
    {
      float pre = 0.f;
      #pragma unroll
      for (int q = 0; q < 16; ++q) pre += pred[q][ub][un];
      #pragma unroll
      for (int j = 0; j < NIN; ++j) pre = fmaf(ubuf[ub][j], winp_s[un][j], pre);
      const float sn = 0.9f * scur + 0.1f * (fmaxf(pre, 0.f) + rnv);
      __hip_atomic_store(&states[((size_t)(g * GG + ub) * TT + t + 1) * NN + ung],
                         sn, __ATOMIC_RELAXED, __HIP_MEMORY_SCOPE_SYSTEM);
      s_own[ub][un] = sn;
      scur = sn;
    }
    __syncthreads();  // #2: payload drained (vmcnt) + s_own/pred safe
    if (tid == 0)
      __hip_atomic_store(&flags[myflag], t + 1, __ATOMIC_RELAXED,
                         __HIP_MEMORY_SCOPE_SYSTEM);
  }
}

// outputs[b][t] = dot(states[b][t][:], Wout) -- one wave per row
__global__ __launch_bounds__(256)
void out_proj(const float* __restrict__ states, const float* __restrict__ Wout,
              float* __restrict__ outputs) {
  const int lane = threadIdx.x & 63;
  const size_t row = (size_t)blockIdx.x * 4 + (threadIdx.x >> 6);
  if (row >= (size_t)BB * TT) return;
  const float* sr = states + row * NN;
  float acc = 0.f;
  #pragma unroll
  for (int h = 0; h < 2; ++h) {
    const float4 sv = *reinterpret_cast<const float4*>(sr + h * 256 + lane * 4);
    const float4 wv = *reinterpret_cast<const float4*>(Wout + h * 256 + lane * 4);
    acc = fmaf(sv.x, wv.x, acc);
    acc = fmaf(sv.y, wv.y, acc);
    acc = fmaf(sv.z, wv.z, acc);
    acc = fmaf(sv.w, wv.w, acc);
  }
  acc = wave_sum(acc);
  if (lane == 0) outputs[row] = acc;
}

// ---------------- fallback: proven R1 kernel (ws too small) ----------------
__global__ __launch_bounds__(512)
void rnn_fused(const float* __restrict__ u, const float* __restrict__ rnz,
               const float* __restrict__ inz, const float* __restrict__ Wsrc,
               const float* __restrict__ Winp, const float* __restrict__ Wout,
               const float* __restrict__ yinit,
               float* __restrict__ states, float* __restrict__ outputs) {
  const int tid = threadIdx.x;
  const int n4 = tid & 127;
  const int kc = tid >> 7;
  const int b0 = blockIdx.x * 2;
  const int b1 = b0 + 1;

  __shared__ __align__(16) float s[2][NN];
  __shared__ __align__(16) float red[2][128][20];
  __shared__ float ubuf[2 * NIN];
  __shared__ float outred[2][8];

  float wi[NIN];
  #pragma unroll
  for (int j = 0; j < NIN; ++j) wi[j] = Winp[tid * NIN + j];
  const float wo = Wout[tid];
  const float yv = yinit[tid];

  s[0][tid] = yv;
  s[1][tid] = yv;
  states[(size_t)(b0 * TT) * NN + tid] = yv;
  states[(size_t)(b1 * TT) * NN + tid] = yv;
  {
    float pzz = wave_sum(yv * wo);
    if ((tid & 63) == 0) outred[0][tid >> 6] = pzz;
  }
  __syncthreads();
  if (tid < 2) {
    float a = 0.f;
    #pragma unroll
    for (int wq = 0; wq < 8; ++wq) a += outred[0][wq];
    outputs[(tid ? b1 : b0) * TT] = a;
  }
  __syncthreads();

  for (int t = 0; t < TT - 1; ++t) {
    const float rn0 = rnz[(size_t)(b0 * TT + t) * NN + tid];
    const float rn1 = rnz[(size_t)(b1 * TT + t) * NN + tid];
    float uv = 0.f;
    if (tid < 2 * NIN) {
      const int b = (tid < NIN) ? b0 : b1;
      const int j = (tid < NIN) ? tid : tid - NIN;
      const int idx = (b * TT + t) * NIN + j;
      uv = u[idx] + inz[idx];
    }
    float a0[4] = {0.f, 0.f, 0.f, 0.f};
    float a1[4] = {0.f, 0.f, 0.f, 0.f};
    const int kbase0 = kc * 128;
    #pragma unroll 4
    for (int j4 = 0; j4 < 32; ++j4) {
      const int kb = kbase0 + j4 * 4;
      const float4 s0v = *reinterpret_cast<const float4*>(&s[0][kb]);
      const float4 s1v = *reinterpret_cast<const float4*>(&s[1][kb]);
      const float s0a[4] = {s0v.x, s0v.y, s0v.z, s0v.w};
      const float s1a[4] = {s1v.x, s1v.y, s1v.z, s1v.w};
      #pragma unroll
      for (int jj = 0; jj < 4; ++jj) {
        const int k = kb + jj;
        const float* pw = Wsrc + (size_t)(n4 << 2) * NN + k;
        float4 wv;
        wv.x = pw[0]; wv.y = pw[NN]; wv.z = pw[2 * NN]; wv.w = pw[3 * NN];
        a0[0] = fmaf(wv.x, s0a[jj], a0[0]);
        a0[1] = fmaf(wv.y, s0a[jj], a0[1]);
        a0[2] = fmaf(wv.z, s0a[jj], a0[2]);
        a0[3] = fmaf(wv.w, s0a[jj], a0[3]);
        a1[0] = fmaf(wv.x, s1a[jj], a1[0]);
        a1[1] = fmaf(wv.y, s1a[jj], a1[1]);
        a1[2] = fmaf(wv.z, s1a[jj], a1[2]);
        a1[3] = fmaf(wv.w, s1a[jj], a1[3]);
      }
    }
    if (tid < 2 * NIN) ubuf[tid] = uv;
    *reinterpret_cast<float4*>(&red[0][n4][kc << 2]) =
        make_float4(a0[0], a0[1], a0[2], a0[3]);
    *reinterpret_cast<float4*>(&red[1][n4][kc << 2]) =
        make_float4(a1[0], a1[1], a1[2], a1[3]);
    __syncthreads();
    const int n = tid;
    const int r = n >> 2, c = n & 3;
    float pre0 = (red[0][r][c] + red[0][r][4 + c]) +
                 (red[0][r][8 + c] + red[0][r][12 + c]);
    float pre1 = (red[1][r][c] + red[1][r][4 + c]) +
                 (red[1][r][8 + c] + red[1][r][12 + c]);
    #pragma unroll
    for (int j = 0; j < NIN; ++j) {
      pre0 = fmaf(ubuf[j], wi[j], pre0);
      pre1 = fmaf(ubuf[NIN + j], wi[j], pre1);
    }
    const float sn0 = 0.9f * s[0][n] + 0.1f * (fmaxf(pre0, 0.f) + rn0);
    const float sn1 = 0.9f * s[1][n] + 0.1f * (fmaxf(pre1, 0.f) + rn1);
    states[(size_t)(b0 * TT + t + 1) * NN + n] = sn0;
    states[(size_t)(b1 * TT + t + 1) * NN + n] = sn1;
    s[0][n] = sn0;
    s[1][n] = sn1;
    float p0 = wave_sum(sn0 * wo);
    float p1 = wave_sum(sn1 * wo);
    if ((tid & 63) == 0) {
      outred[0][tid >> 6] = p0;
      outred[1][tid >> 6] = p1;
    }
    __syncthreads();
    if (tid < 2) {
      float a = 0.f;
      #pragma unroll
      for (int wq = 0; wq < 8; ++wq) a += outred[tid][wq];
      outputs[(tid ? b1 : b0) * TT + t + 1] = a;
    }
  }
}

extern "C" void kernel_launch(void* const* d_in, const int* in_sizes, int n_in,
                              void* d_out, int out_size, void* d_ws, size_t ws_size,
                              hipStream_t stream) {
  const float* u    = (const float*)d_in[0];
  const float* rnz  = (const float*)d_in[1];
  const float* inz  = (const float*)d_in[2];
  const float* Wrec = (const float*)d_in[3];
  const float* Winp = (const float*)d_in[4];
  const float* Wout = (const float*)d_in[5];
  const float* yin  = (const float*)d_in[6];
  float* states  = (float*)d_out;
  float* outputs = states + (size_t)BB * TT * NN;

  if (ws_size >= WS_NEED) {
    int* flags = (int*)d_ws;
    init_flags<<<1, 128, 0, stream>>>(flags);
    rnn_pipe<<<NWG, 512, 0, stream>>>(u, rnz, inz, Wrec, Winp, yin,
                                      states, flags);
    out_proj<<<(BB * TT + 3) / 4, 256, 0, stream>>>(states, Wout, outputs);
  } else {
    rnn_fused<<<BB / 2, 512, 0, stream>>>(u, rnz, inz, Wrec, Winp, Wout,
                                          yin, states, outputs);
  }
}

// Round 12
// 2988.374 us; speedup vs baseline: 1.3752x; 1.3752x over previous
//
#include <hip/hip_runtime.h>

// RNN: s_{t+1} = 0.9*s + 0.1*(relu(s@Wrec^T + (u+inz)@Winp^T) + rn)
// d_out = states (B,T,N) fp32 then outputs (B,T,1) fp32, flat-concat.
//
// R12: resident-W, n-partitioned, FUSED tag+payload IF exchange.
//   R9  (4.06 ms): flags + staged payload = 2 dependent IF round trips
//                  + 4 barriers per step.
//   R11 (hung): sc0/L2 fast path gated on XCC_ID -- non-coherent spin.
//               Lesson: cross-XCD exchange must go through IF, and
//               liveness must never depend on unverified introspection.
//   Here: each exchanged s value is ONE 64-bit word (tag<<32 | fp32):
//   writer publishes with a single system-scope relaxed atomic store;
//   readers poll the word until tag >= t. Flag==payload -> one IF trip,
//   no drain-before-flag, no tid0 fan-in, 2 barriers/step.
//   - xbuf[par][g][b][n] (1 MB), par = t&1. WAR-safe 2-deep: writer
//     overwrites parity slot of s_t with s_{t+2} only after it fetched
//     peers' s_{t+1}, which peers publish only after consuming s_t.
//     tag >= t  ==>  tag == t (t+1 lands in the other parity).
//   - Replay-safe: init kernel (in-stream, captured) resets all tags to
//     -1 each call; harness 0xAA poison also parses as tag < 0.
//   - states is now a PLAIN cached store (pure output, nobody reads it
//     during the recurrence); out_proj projects it afterwards.
//   - W resident: w[4][8] float4/thread, pinned by scalar asm "+v"
//     (R6: unpinned W was re-streamed from L2 every step).
// Fallback: proven R1-style kernel if workspace < 1 MB.

#define NN 512
#define BB 128
#define TT 1000
#define NIN 6
#define PP 4                    // n-slices (WGs per group)
#define GG 4                    // batches per group
#define NGRP (BB / GG)          // 32 groups
#define NWG (PP * NGRP)         // 128 workgroups
#define SLICE (NN / PP)         // 128
#define XWORDS (2 * NGRP * GG * NN)          // 131072 words = 1 MB
#define WS_NEED (XWORDS * sizeof(unsigned long long))

typedef unsigned long long u64;

__global__ void init_xbuf(u64* xbuf) {
  const int i = blockIdx.x * 256 + threadIdx.x;
  // tag = -1 in high 32 bits; value irrelevant
  if (i < XWORDS / 2) {
    reinterpret_cast<u64*>(xbuf)[i] = 0xFFFFFFFF00000000ULL;
    reinterpret_cast<u64*>(xbuf)[i + XWORDS / 2] = 0xFFFFFFFF00000000ULL;
  }
}

__device__ __forceinline__ float wave_sum(float v) {
  #pragma unroll
  for (int off = 32; off > 0; off >>= 1) v += __shfl_xor(v, off, 64);
  return v;
}

// empty asm with tied SCALAR outputs: values become opaque (non-remat).
__device__ __forceinline__ void pin4(float4& a, float4& b, float4& c, float4& d) {
  asm volatile("" : "+v"(a.x), "+v"(a.y), "+v"(a.z), "+v"(a.w),
                    "+v"(b.x), "+v"(b.y), "+v"(b.z), "+v"(b.w),
                    "+v"(c.x), "+v"(c.y), "+v"(c.z), "+v"(c.w),
                    "+v"(d.x), "+v"(d.y), "+v"(d.z), "+v"(d.w));
}

__device__ __forceinline__ u64 xld(const u64* p) {
  return __hip_atomic_load(p, __ATOMIC_RELAXED, __HIP_MEMORY_SCOPE_SYSTEM);
}
__device__ __forceinline__ void xst(u64* p, u64 v) {
  __hip_atomic_store(p, v, __ATOMIC_RELAXED, __HIP_MEMORY_SCOPE_SYSTEM);
}

__global__ __launch_bounds__(512, 1)
void rnn_tagx(const float* __restrict__ u, const float* __restrict__ rnz,
              const float* __restrict__ inz, const float* __restrict__ Wrec,
              const float* __restrict__ Winp, const float* __restrict__ yinit,
              float* __restrict__ states, u64* __restrict__ xbuf) {
  const int tid = threadIdx.x;
  // bid remap: group's 4 WGs share bid&7 (XCD locality hint only; the
  // protocol is placement-independent -- all exchange goes through IF).
  const int xcd = blockIdx.x & 7;
  const int rest = blockIdx.x >> 3;     // 0..15
  const int p = rest & 3;               // my n-slice
  const int g = (rest >> 2) * 8 + xcd;  // my group 0..31

  // phase-A mapping: thread (nq, ks) = 4 n-rows x 32-k window x 4 batches
  const int nq = tid & 31;
  const int n0 = nq << 2;               // local n base
  const int ks = tid >> 5;              // k-split 0..15 (wave-uniform x2)
  const int k0 = ks << 5;               // global k base
  // update/fetch mapping: thread = (batch, local n)
  const int ub = tid >> 7;
  const int un = tid & 127;
  const int ung = p * SLICE + un;

  __shared__ __align__(16) float pred[16][GG][SLICE];  // 32 KB
  __shared__ __align__(16) float s_all[GG][NN];        // 8 KB
  __shared__ float winp_s[SLICE][NIN];                 // 3 KB
  __shared__ float ubuf[2][GG][NIN];                   // parity-buffered

  // ---- one-time: W fragment (4 rows x 32 k), Winp ----
  float4 w[4][8];
  #pragma unroll
  for (int i = 0; i < 4; ++i) {
    const float* wr = Wrec + (size_t)(p * SLICE + n0 + i) * NN + k0;
    #pragma unroll
    for (int q = 0; q < 8; ++q)
      w[i][q] = *reinterpret_cast<const float4*>(wr + 4 * q);
  }
  for (int i = tid; i < SLICE * NIN; i += 512) {
    const int r = i / NIN, j = i - r * NIN;
    winp_s[r][j] = Winp[(p * SLICE + r) * NIN + j];
  }
  // s_0 = y_init everywhere (local knowledge: no exchange needed at t=0)
  for (int i = tid; i < GG * NN; i += 512)
    s_all[i >> 9][i & 511] = yinit[i & 511];
  float scur = yinit[ung];
  states[(size_t)(g * GG + ub) * TT * NN + ung] = scur;  // row 0, plain
  __syncthreads();

  for (int t = 0; t < TT - 1; ++t) {
    const int par = t & 1;

    // pin W live (R6: unpinned W was re-streamed from L2 every step)
    #pragma unroll
    for (int i = 0; i < 4; ++i) {
      pin4(w[i][0], w[i][1], w[i][2], w[i][3]);
      pin4(w[i][4], w[i][5], w[i][6], w[i][7]);
    }

    // early per-step loads (plain, cached; consumed after barB)
    const float rnv = rnz[((size_t)(g * GG + ub) * TT + t) * NN + ung];
    if (tid < GG * NIN) {
      const int b = tid / NIN, j = tid - b * NIN;
      const size_t idx = ((size_t)(g * GG + b) * TT + t) * NIN + j;
      ubuf[par][b][j] = u[idx] + inz[idx];
    }

    // ---- fetch: poll fused (tag|payload) words for 3 peer slices ----
    if (t > 0) {
      const u64* xb = xbuf + (((size_t)par * NGRP + g) * GG + ub) * NN;
      const int q0 = (p + 1) & 3, q1 = (p + 2) & 3, q2 = (p + 3) & 3;
      const u64* p0 = xb + q0 * SLICE + un;
      const u64* p1 = xb + q1 * SLICE + un;
      const u64* p2 = xb + q2 * SLICE + un;
      u64 v0 = xld(p0), v1 = xld(p1), v2 = xld(p2);  // 3 in flight
      while ((int)(v0 >> 32) < t) { __builtin_amdgcn_s_sleep(1); v0 = xld(p0); }
      while ((int)(v1 >> 32) < t) { __builtin_amdgcn_s_sleep(1); v1 = xld(p1); }
      while ((int)(v2 >> 32) < t) { __builtin_amdgcn_s_sleep(1); v2 = xld(p2); }
      s_all[ub][q0 * SLICE + un] = __uint_as_float((unsigned)v0);
      s_all[ub][q1 * SLICE + un] = __uint_as_float((unsigned)v1);
      s_all[ub][q2 * SLICE + un] = __uint_as_float((unsigned)v2);
    }
    __syncthreads();  // barA: s_all complete (own slice from last update)

    // ---- phase A: 4 n x 32 k x 4 b partial dots (512 fmaf) ----
    float a0[GG], a1[GG], a2[GG], a3[GG];
    #pragma unroll
    for (int b = 0; b < GG; ++b) { a0[b] = 0.f; a1[b] = 0.f; a2[b] = 0.f; a3[b] = 0.f; }
    #pragma unroll
    for (int b = 0; b < GG; ++b) {
      #pragma unroll
      for (int q = 0; q < 8; ++q) {
        const float4 sv = *reinterpret_cast<const float4*>(&s_all[b][k0 + 4 * q]);
        a0[b] = fmaf(w[0][q].x, sv.x, a0[b]); a0[b] = fmaf(w[0][q].y, sv.y, a0[b]);
        a0[b] = fmaf(w[0][q].z, sv.z, a0[b]); a0[b] = fmaf(w[0][q].w, sv.w, a0[b]);
        a1[b] = fmaf(w[1][q].x, sv.x, a1[b]); a1[b] = fmaf(w[1][q].y, sv.y, a1[b]);
        a1[b] = fmaf(w[1][q].z, sv.z, a1[b]); a1[b] = fmaf(w[1][q].w, sv.w, a1[b]);
        a2[b] = fmaf(w[2][q].x, sv.x, a2[b]); a2[b] = fmaf(w[2][q].y, sv.y, a2[b]);
        a2[b] = fmaf(w[2][q].z, sv.z, a2[b]); a2[b] = fmaf(w[2][q].w, sv.w, a2[b]);
        a3[b] = fmaf(w[3][q].x, sv.x, a3[b]); a3[b] = fmaf(w[3][q].y, sv.y, a3[b]);
        a3[b] = fmaf(w[3][q].z, sv.z, a3[b]); a3[b] = fmaf(w[3][q].w, sv.w, a3[b]);
      }
    }
    #pragma unroll
    for (int b = 0; b < GG; ++b)
      *reinterpret_cast<float4*>(&pred[ks][b][n0]) =
          make_float4(a0[b], a1[b], a2[b], a3[b]);
    __syncthreads();  // barB: pred + ubuf visible

    // ---- update: thread (ub, un); publish fused word; plain states ----
    {
      float pre = 0.f;
      #pragma unroll
      for (int q = 0; q < 16; ++q) pre += pred[q][ub][un];
      #pragma unroll
      for (int j = 0; j < NIN; ++j)
        pre = fmaf(ubuf[par][ub][j], winp_s[un][j], pre);
      const float sn = 0.9f * scur + 0.1f * (fmaxf(pre, 0.f) + rnv);
      states[((size_t)(g * GG + ub) * TT + t + 1) * NN + ung] = sn;
      const u64 pw = ((u64)(unsigned)(t + 1) << 32) | __float_as_uint(sn);
      xst(&xbuf[(((size_t)((t + 1) & 1) * NGRP + g) * GG + ub) * NN + ung], pw);
      asm volatile("" ::: "memory");  // publish not reordered past polls
      s_all[ub][ung] = sn;
      scur = sn;
    }
    // no barrier here: next fetch writes peer LDS slices (disjoint from
    // own-slice update writes); pred overwrite is fenced by barA+barB.
  }
}

// outputs[b][t] = dot(states[b][t][:], Wout) -- one wave per row
__global__ __launch_bounds__(256)
void out_proj(const float* __restrict__ states, const float* __restrict__ Wout,
              float* __restrict__ outputs) {
  const int lane = threadIdx.x & 63;
  const size_t row = (size_t)blockIdx.x * 4 + (threadIdx.x >> 6);
  if (row >= (size_t)BB * TT) return;
  const float* sr = states + row * NN;
  float acc = 0.f;
  #pragma unroll
  for (int h = 0; h < 2; ++h) {
    const float4 sv = *reinterpret_cast<const float4*>(sr + h * 256 + lane * 4);
    const float4 wv = *reinterpret_cast<const float4*>(Wout + h * 256 + lane * 4);
    acc = fmaf(sv.x, wv.x, acc);
    acc = fmaf(sv.y, wv.y, acc);
    acc = fmaf(sv.z, wv.z, acc);
    acc = fmaf(sv.w, wv.w, acc);
  }
  acc = wave_sum(acc);
  if (lane == 0) outputs[row] = acc;
}

// ---------------- fallback: proven R1 kernel (ws too small) ----------------
__global__ __launch_bounds__(512)
void rnn_fused(const float* __restrict__ u, const float* __restrict__ rnz,
               const float* __restrict__ inz, const float* __restrict__ Wsrc,
               const float* __restrict__ Winp, const float* __restrict__ Wout,
               const float* __restrict__ yinit,
               float* __restrict__ states, float* __restrict__ outputs) {
  const int tid = threadIdx.x;
  const int n4 = tid & 127;
  const int kc = tid >> 7;
  const int b0 = blockIdx.x * 2;
  const int b1 = b0 + 1;

  __shared__ __align__(16) float s[2][NN];
  __shared__ __align__(16) float red[2][128][20];
  __shared__ float ubf[2 * NIN];
  __shared__ float outred[2][8];

  float wi[NIN];
  #pragma unroll
  for (int j = 0; j < NIN; ++j) wi[j] = Winp[tid * NIN + j];
  const float wo = Wout[tid];
  const float yv = yinit[tid];

  s[0][tid] = yv;
  s[1][tid] = yv;
  states[(size_t)(b0 * TT) * NN + tid] = yv;
  states[(size_t)(b1 * TT) * NN + tid] = yv;
  {
    float pzz = wave_sum(yv * wo);
    if ((tid & 63) == 0) outred[0][tid >> 6] = pzz;
  }
  __syncthreads();
  if (tid < 2) {
    float a = 0.f;
    #pragma unroll
    for (int wq = 0; wq < 8; ++wq) a += outred[0][wq];
    outputs[(tid ? b1 : b0) * TT] = a;
  }
  __syncthreads();

  for (int t = 0; t < TT - 1; ++t) {
    const float rn0 = rnz[(size_t)(b0 * TT + t) * NN + tid];
    const float rn1 = rnz[(size_t)(b1 * TT + t) * NN + tid];
    float uv = 0.f;
    if (tid < 2 * NIN) {
      const int b = (tid < NIN) ? b0 : b1;
      const int j = (tid < NIN) ? tid : tid - NIN;
      const int idx = (b * TT + t) * NIN + j;
      uv = u[idx] + inz[idx];
    }
    float a0[4] = {0.f, 0.f, 0.f, 0.f};
    float a1[4] = {0.f, 0.f, 0.f, 0.f};
    const int kbase0 = kc * 128;
    #pragma unroll 4
    for (int j4 = 0; j4 < 32; ++j4) {
      const int kb = kbase0 + j4 * 4;
      const float4 s0v = *reinterpret_cast<const float4*>(&s[0][kb]);
      const float4 s1v = *reinterpret_cast<const float4*>(&s[1][kb]);
      const float s0a[4] = {s0v.x, s0v.y, s0v.z, s0v.w};
      const float s1a[4] = {s1v.x, s1v.y, s1v.z, s1v.w};
      #pragma unroll
      for (int jj = 0; jj < 4; ++jj) {
        const int k = kb + jj;
        const float* pw = Wsrc + (size_t)(n4 << 2) * NN + k;
        float4 wv;
        wv.x = pw[0]; wv.y = pw[NN]; wv.z = pw[2 * NN]; wv.w = pw[3 * NN];
        a0[0] = fmaf(wv.x, s0a[jj], a0[0]);
        a0[1] = fmaf(wv.y, s0a[jj], a0[1]);
        a0[2] = fmaf(wv.z, s0a[jj], a0[2]);
        a0[3] = fmaf(wv.w, s0a[jj], a0[3]);
        a1[0] = fmaf(wv.x, s1a[jj], a1[0]);
        a1[1] = fmaf(wv.y, s1a[jj], a1[1]);
        a1[2] = fmaf(wv.z, s1a[jj], a1[2]);
        a1[3] = fmaf(wv.w, s1a[jj], a1[3]);
      }
    }
    if (tid < 2 * NIN) ubf[tid] = uv;
    *reinterpret_cast<float4*>(&red[0][n4][kc << 2]) =
        make_float4(a0[0], a0[1], a0[2], a0[3]);
    *reinterpret_cast<float4*>(&red[1][n4][kc << 2]) =
        make_float4(a1[0], a1[1], a1[2], a1[3]);
    __syncthreads();
    const int n = tid;
    const int r = n >> 2, c = n & 3;
    float pre0 = (red[0][r][c] + red[0][r][4 + c]) +
                 (red[0][r][8 + c] + red[0][r][12 + c]);
    float pre1 = (red[1][r][c] + red[1][r][4 + c]) +
                 (red[1][r][8 + c] + red[1][r][12 + c]);
    #pragma unroll
    for (int j = 0; j < NIN; ++j) {
      pre0 = fmaf(ubf[j], wi[j], pre0);
      pre1 = fmaf(ubf[NIN + j], wi[j], pre1);
    }
    const float sn0 = 0.9f * s[0][n] + 0.1f * (fmaxf(pre0, 0.f) + rn0);
    const float sn1 = 0.9f * s[1][n] + 0.1f * (fmaxf(pre1, 0.f) + rn1);
    states[(size_t)(b0 * TT + t + 1) * NN + n] = sn0;
    states[(size_t)(b1 * TT + t + 1) * NN + n] = sn1;
    s[0][n] = sn0;
    s[1][n] = sn1;
    float p0 = wave_sum(sn0 * wo);
    float p1 = wave_sum(sn1 * wo);
    if ((tid & 63) == 0) {
      outred[0][tid >> 6] = p0;
      outred[1][tid >> 6] = p1;
    }
    __syncthreads();
    if (tid < 2) {
      float a = 0.f;
      #pragma unroll
      for (int wq = 0; wq < 8; ++wq) a += outred[tid][wq];
      outputs[(tid ? b1 : b0) * TT + t + 1] = a;
    }
  }
}

extern "C" void kernel_launch(void* const* d_in, const int* in_sizes, int n_in,
                              void* d_out, int out_size, void* d_ws, size_t ws_size,
                              hipStream_t stream) {
  const float* u    = (const float*)d_in[0];
  const float* rnz  = (const float*)d_in[1];
  const float* inz  = (const float*)d_in[2];
  const float* Wrec = (const float*)d_in[3];
  const float* Winp = (const float*)d_in[4];
  const float* Wout = (const float*)d_in[5];
  const float* yin  = (const float*)d_in[6];
  float* states  = (float*)d_out;
  float* outputs = states + (size_t)BB * TT * NN;

  if (ws_size >= WS_NEED) {
    u64* xbuf = (u64*)d_ws;
    init_xbuf<<<(XWORDS / 2 + 255) / 256, 256, 0, stream>>>(xbuf);
    rnn_tagx<<<NWG, 512, 0, stream>>>(u, rnz, inz, Wrec, Winp, yin,
                                      states, xbuf);
    out_proj<<<(BB * TT + 3) / 4, 256, 0, stream>>>(states, Wout, outputs);
  } else {
    rnn_fused<<<BB / 2, 512, 0, stream>>>(u, rnz, inz, Wrec, Winp, Wout,
                                          yin, states, outputs);
  }
}